// Round 1
// baseline (1124.226 us; speedup 1.0000x reference)
//
#include <hip/hip_runtime.h>
#include <hip/hip_bf16.h>
#include <math.h>

#define NEG -1e9f
#define SCAN_CHUNK 2048

// ---------------- CSR build ----------------

__global__ void hist_kernel(const int* __restrict__ dst, int* __restrict__ counts, int e) {
    int i = blockIdx.x * blockDim.x + threadIdx.x;
    if (i < e) atomicAdd(&counts[dst[i]], 1);
}

__global__ __launch_bounds__(256) void scan_block_sums(const int* __restrict__ counts,
                                                       int* __restrict__ bsum, int n) {
    __shared__ int sd[256];
    int t = threadIdx.x;
    int base = blockIdx.x * SCAN_CHUNK + t * 8;
    int s = 0;
#pragma unroll
    for (int j = 0; j < 8; ++j) {
        int idx = base + j;
        if (idx < n) s += counts[idx];
    }
    sd[t] = s;
    __syncthreads();
    for (int off = 128; off > 0; off >>= 1) {
        if (t < off) sd[t] += sd[t + off];
        __syncthreads();
    }
    if (t == 0) bsum[blockIdx.x] = sd[0];
}

__global__ void scan_serial(int* bsum, int nb) {
    if (threadIdx.x == 0 && blockIdx.x == 0) {
        int run = 0;
        for (int i = 0; i < nb; ++i) { int tv = bsum[i]; bsum[i] = run; run += tv; }
    }
}

__global__ __launch_bounds__(256) void scan_write(const int* __restrict__ counts,
                                                  const int* __restrict__ bsum,
                                                  int* __restrict__ row_ptr,
                                                  int* __restrict__ cursor,
                                                  int n, int total) {
    __shared__ int sd[256];
    int t = threadIdx.x;
    int base = blockIdx.x * SCAN_CHUNK + t * 8;
    int v[8];
    int s = 0;
#pragma unroll
    for (int j = 0; j < 8; ++j) {
        int idx = base + j;
        v[j] = (idx < n) ? counts[idx] : 0;
        s += v[j];
    }
    sd[t] = s;
    __syncthreads();
    // Hillis-Steele inclusive scan over the 256 thread sums
    for (int off = 1; off < 256; off <<= 1) {
        int tmp = 0;
        if (t >= off) tmp = sd[t - off];
        __syncthreads();
        if (t >= off) sd[t] += tmp;
        __syncthreads();
    }
    int run = bsum[blockIdx.x] + sd[t] - s;  // exclusive prefix for this thread
#pragma unroll
    for (int j = 0; j < 8; ++j) {
        int idx = base + j;
        if (idx < n) {
            row_ptr[idx] = run;
            cursor[idx] = run;
            run += v[j];
        }
    }
    if (blockIdx.x == 0 && t == 0) row_ptr[n] = total;
}

__global__ void fill_csr(const int* __restrict__ dst, int* cursor,
                         int* __restrict__ csr, int e) {
    int i = blockIdx.x * blockDim.x + threadIdx.x;
    if (i < e) {
        int p = atomicAdd(&cursor[dst[i]], 1);
        csr[p] = i;
    }
}

// ---------------- QKV projection (fp32, vector ALU) ----------------
// One block = 32 node rows. Load x tile to LDS, each thread owns one output
// column for 16 rows, accumulating q,k,v simultaneously (reuses W loads).

__global__ __launch_bounds__(256) void qkv_gemm(
    const float* __restrict__ x,
    const float* __restrict__ Wq, const float* __restrict__ bq,
    const float* __restrict__ Wk, const float* __restrict__ bk,
    const float* __restrict__ Wv, const float* __restrict__ bv,
    float* __restrict__ qb, float* __restrict__ kb, float* __restrict__ vb,
    int n) {
    __shared__ __align__(16) float xs[32 * 128];
    int t = threadIdx.x;
    int n0 = blockIdx.x * 32;
    int nrows = n - n0; if (nrows > 32) nrows = 32;

    // load 32x128 tile (contiguous region) as float4
    const float4* xsrc = (const float4*)(x + (size_t)n0 * 128);
    float4* xd = (float4*)xs;
    for (int i = t; i < 1024; i += 256) {
        int row = i >> 5;  // 32 float4 per row
        if (row < nrows) xd[i] = xsrc[i];
        else xd[i] = make_float4(0.f, 0.f, 0.f, 0.f);
    }
    __syncthreads();

    int c = t & 127;   // output column
    int g = t >> 7;    // row group: 0 -> rows 0..15, 1 -> rows 16..31
    float aq[16], ak[16], av[16];
    float bqv = bq[c], bkv = bk[c], bvv = bv[c];
#pragma unroll
    for (int j = 0; j < 16; ++j) { aq[j] = bqv; ak[j] = bkv; av[j] = bvv; }

    const float* xbase = xs + g * 16 * 128;
    for (int i = 0; i < 128; i += 4) {
        float wq0 = Wq[(i + 0) * 128 + c], wq1 = Wq[(i + 1) * 128 + c];
        float wq2 = Wq[(i + 2) * 128 + c], wq3 = Wq[(i + 3) * 128 + c];
        float wk0 = Wk[(i + 0) * 128 + c], wk1 = Wk[(i + 1) * 128 + c];
        float wk2 = Wk[(i + 2) * 128 + c], wk3 = Wk[(i + 3) * 128 + c];
        float wv0 = Wv[(i + 0) * 128 + c], wv1 = Wv[(i + 1) * 128 + c];
        float wv2 = Wv[(i + 2) * 128 + c], wv3 = Wv[(i + 3) * 128 + c];
#pragma unroll
        for (int j = 0; j < 16; ++j) {
            float4 xv = *(const float4*)(xbase + j * 128 + i);
            aq[j] = fmaf(xv.x, wq0, fmaf(xv.y, wq1, fmaf(xv.z, wq2, fmaf(xv.w, wq3, aq[j]))));
            ak[j] = fmaf(xv.x, wk0, fmaf(xv.y, wk1, fmaf(xv.z, wk2, fmaf(xv.w, wk3, ak[j]))));
            av[j] = fmaf(xv.x, wv0, fmaf(xv.y, wv1, fmaf(xv.z, wv2, fmaf(xv.w, wv3, av[j]))));
        }
    }

#pragma unroll
    for (int j = 0; j < 16; ++j) {
        int row = n0 + g * 16 + j;
        if (row < n) {
            qb[(size_t)row * 128 + c] = aq[j];
            kb[(size_t)row * 128 + c] = ak[j];
            vb[(size_t)row * 128 + c] = av[j];
        }
    }
}

// ---------------- Node-centric attention ----------------
// One thread per (node, head): 8 threads/node, 32 nodes/block.
// Loop A: scores + running max (writes raw scores to attn buffer)
// Loop B: exp-sum + weighted V accumulate
// Loop C: normalize attn

__global__ __launch_bounds__(256) void edge_attn(
    const float* __restrict__ qbuf, const float* __restrict__ kbuf,
    const float* __restrict__ vbuf, const float* __restrict__ pi,
    const float* __restrict__ view_w, const int* __restrict__ src,
    const int* __restrict__ row_ptr, const int* __restrict__ csr,
    float* __restrict__ node_out, float* attn_out, int n) {
    int t = threadIdx.x;
    int node = blockIdx.x * 32 + (t >> 3);
    int h = t & 7;
    if (node >= n) return;

    const float4* qp = (const float4*)(qbuf + (size_t)node * 128 + h * 16);
    float4 q0 = qp[0], q1 = qp[1], q2 = qp[2], q3 = qp[3];
    float p0 = pi[node * 24 + h * 3 + 0];
    float p1 = pi[node * 24 + h * 3 + 1];
    float p2 = pi[node * 24 + h * 3 + 2];
    int beg = row_ptr[node], end = row_ptr[node + 1];

    // Loop A: scores, running max
    float m = -INFINITY;
    for (int i = beg; i < end; ++i) {
        int e = csr[i];
        int s0 = src[e];
        float w0 = view_w[e * 3 + 0], w1 = view_w[e * 3 + 1], w2 = view_w[e * 3 + 2];
        float mix = fmaf(p0, w0, fmaf(p1, w1, p2 * w2));
        const float4* kp = (const float4*)(kbuf + (size_t)s0 * 128 + h * 16);
        float4 k0 = kp[0], k1 = kp[1], k2 = kp[2], k3 = kp[3];
        float dot = q0.x * k0.x + q0.y * k0.y + q0.z * k0.z + q0.w * k0.w
                  + q1.x * k1.x + q1.y * k1.y + q1.z * k1.z + q1.w * k1.w
                  + q2.x * k2.x + q2.y * k2.y + q2.z * k2.z + q2.w * k2.w
                  + q3.x * k3.x + q3.y * k3.y + q3.z * k3.z + q3.w * k3.w;
        float s;
        if (mix > 0.f) s = dot * 0.25f + logf(fmaxf(mix, 1e-8f));
        else s = NEG;
        m = fmaxf(m, s);
        attn_out[(size_t)e * 8 + h] = s;
    }

    // Loop B: exp-sum + weighted V accumulation
    float l = 0.f;
    float4 a0 = make_float4(0.f, 0.f, 0.f, 0.f);
    float4 a1 = a0, a2 = a0, a3 = a0;
    for (int i = beg; i < end; ++i) {
        int e = csr[i];
        int s0 = src[e];
        float s = attn_out[(size_t)e * 8 + h];
        float w = (s <= 0.5f * NEG) ? 0.f : expf(s - m);
        l += w;
        const float4* vp = (const float4*)(vbuf + (size_t)s0 * 128 + h * 16);
        float4 v0 = vp[0], v1 = vp[1], v2 = vp[2], v3 = vp[3];
        a0.x = fmaf(w, v0.x, a0.x); a0.y = fmaf(w, v0.y, a0.y);
        a0.z = fmaf(w, v0.z, a0.z); a0.w = fmaf(w, v0.w, a0.w);
        a1.x = fmaf(w, v1.x, a1.x); a1.y = fmaf(w, v1.y, a1.y);
        a1.z = fmaf(w, v1.z, a1.z); a1.w = fmaf(w, v1.w, a1.w);
        a2.x = fmaf(w, v2.x, a2.x); a2.y = fmaf(w, v2.y, a2.y);
        a2.z = fmaf(w, v2.z, a2.z); a2.w = fmaf(w, v2.w, a2.w);
        a3.x = fmaf(w, v3.x, a3.x); a3.y = fmaf(w, v3.y, a3.y);
        a3.z = fmaf(w, v3.z, a3.z); a3.w = fmaf(w, v3.w, a3.w);
    }

    float inv = 1.f / fmaxf(l, 1e-8f);
    float4* op = (float4*)(node_out + (size_t)node * 128 + h * 16);
    op[0] = make_float4(a0.x * inv, a0.y * inv, a0.z * inv, a0.w * inv);
    op[1] = make_float4(a1.x * inv, a1.y * inv, a1.z * inv, a1.w * inv);
    op[2] = make_float4(a2.x * inv, a2.y * inv, a2.z * inv, a2.w * inv);
    op[3] = make_float4(a3.x * inv, a3.y * inv, a3.z * inv, a3.w * inv);

    // Loop C: normalize attn in place
    for (int i = beg; i < end; ++i) {
        int e = csr[i];
        float s = attn_out[(size_t)e * 8 + h];
        float w = (s <= 0.5f * NEG) ? 0.f : expf(s - m);
        attn_out[(size_t)e * 8 + h] = w * inv;
    }
}

// ---------------- launch ----------------

extern "C" void kernel_launch(void* const* d_in, const int* in_sizes, int n_in,
                              void* d_out, int out_size, void* d_ws, size_t ws_size,
                              hipStream_t stream) {
    const float* x  = (const float*)d_in[0];
    const float* pi = (const float*)d_in[1];
    const float* vw = (const float*)d_in[2];
    const float* Wq = (const float*)d_in[3];
    const float* bq = (const float*)d_in[4];
    const float* Wk = (const float*)d_in[5];
    const float* bk = (const float*)d_in[6];
    const float* Wv = (const float*)d_in[7];
    const float* bv = (const float*)d_in[8];
    const int* src  = (const int*)d_in[9];
    const int* dst  = (const int*)d_in[10];

    int n = in_sizes[0] / 128;  // 100000
    int e = in_sizes[9];        // 1600000

    float* qb = (float*)d_ws;
    float* kb = qb + (size_t)n * 128;
    float* vb = kb + (size_t)n * 128;
    int* counts  = (int*)(vb + (size_t)n * 128);
    int* cursor  = counts + n;
    int* row_ptr = cursor + n;
    int* csr     = row_ptr + n + 1;
    int* bsum    = csr + e;

    float* node_out = (float*)d_out;
    float* attn_out = node_out + (size_t)n * 128;

    hipMemsetAsync(counts, 0, (size_t)n * sizeof(int), stream);

    int eb = (e + 255) / 256;
    hist_kernel<<<eb, 256, 0, stream>>>(dst, counts, e);

    int nb = (n + SCAN_CHUNK - 1) / SCAN_CHUNK;  // 49
    scan_block_sums<<<nb, 256, 0, stream>>>(counts, bsum, n);
    scan_serial<<<1, 64, 0, stream>>>(bsum, nb);
    scan_write<<<nb, 256, 0, stream>>>(counts, bsum, row_ptr, cursor, n, e);
    fill_csr<<<eb, 256, 0, stream>>>(dst, cursor, csr, e);

    int gb = (n + 31) / 32;  // 3125
    qkv_gemm<<<gb, 256, 0, stream>>>(x, Wq, bq, Wk, bk, Wv, bv, qb, kb, vb, n);
    edge_attn<<<gb, 256, 0, stream>>>(qb, kb, vb, pi, vw, src, row_ptr, csr,
                                      node_out, attn_out, n);
}

// Round 3
// 738.297 us; speedup vs baseline: 1.5227x; 1.5227x over previous
//
#include <hip/hip_runtime.h>
#include <hip/hip_bf16.h>
#include <math.h>

#define NEG -1e9f
#define SCAN_CHUNK 2048

typedef _Float16 half8 __attribute__((ext_vector_type(8)));
typedef _Float16 half16v __attribute__((ext_vector_type(16)));
typedef float floatx4 __attribute__((ext_vector_type(4)));

// ---------------- CSR build ----------------

__global__ void hist_kernel(const int* __restrict__ dst, int* __restrict__ counts, int e) {
    int i = blockIdx.x * blockDim.x + threadIdx.x;
    if (i < e) atomicAdd(&counts[dst[i]], 1);
}

__global__ __launch_bounds__(256) void scan_block_sums(const int* __restrict__ counts,
                                                       int* __restrict__ bsum, int n) {
    __shared__ int sd[256];
    int t = threadIdx.x;
    int base = blockIdx.x * SCAN_CHUNK + t * 8;
    int s = 0;
#pragma unroll
    for (int j = 0; j < 8; ++j) {
        int idx = base + j;
        if (idx < n) s += counts[idx];
    }
    sd[t] = s;
    __syncthreads();
    for (int off = 128; off > 0; off >>= 1) {
        if (t < off) sd[t] += sd[t + off];
        __syncthreads();
    }
    if (t == 0) bsum[blockIdx.x] = sd[0];
}

// single-wave exclusive scan over nb <= 64 block sums
__global__ void scan_wave(int* bsum, int nb) {
    int lane = threadIdx.x;
    int orig = (lane < nb) ? bsum[lane] : 0;
    int v = orig;
    for (int off = 1; off < 64; off <<= 1) {
        int t = __shfl_up(v, off, 64);
        if (lane >= off) v += t;
    }
    if (lane < nb) bsum[lane] = v - orig;  // exclusive
}

__global__ __launch_bounds__(256) void scan_write(const int* __restrict__ counts,
                                                  const int* __restrict__ bsum,
                                                  int* __restrict__ row_ptr,
                                                  int* __restrict__ cursor,
                                                  int n, int total) {
    __shared__ int sd[256];
    int t = threadIdx.x;
    int base = blockIdx.x * SCAN_CHUNK + t * 8;
    int v[8];
    int s = 0;
#pragma unroll
    for (int j = 0; j < 8; ++j) {
        int idx = base + j;
        v[j] = (idx < n) ? counts[idx] : 0;
        s += v[j];
    }
    sd[t] = s;
    __syncthreads();
    for (int off = 1; off < 256; off <<= 1) {
        int tmp = 0;
        if (t >= off) tmp = sd[t - off];
        __syncthreads();
        if (t >= off) sd[t] += tmp;
        __syncthreads();
    }
    int run = bsum[blockIdx.x] + sd[t] - s;
#pragma unroll
    for (int j = 0; j < 8; ++j) {
        int idx = base + j;
        if (idx < n) {
            row_ptr[idx] = run;
            cursor[idx] = run;
            run += v[j];
        }
    }
    if (blockIdx.x == 0 && t == 0) row_ptr[n] = total;
}

__global__ void fill_csr(const int* __restrict__ dst, int* cursor,
                         int* __restrict__ csr, int e) {
    int i = blockIdx.x * blockDim.x + threadIdx.x;
    if (i < e) {
        int p = atomicAdd(&cursor[dst[i]], 1);
        csr[p] = i;
    }
}

// ---------------- fp16 prep ----------------

__global__ __launch_bounds__(256) void convert_x(const float* __restrict__ x,
                                                 _Float16* __restrict__ xh, int total8) {
    int i = blockIdx.x * blockDim.x + threadIdx.x;
    if (i < total8) {
        const float4* s = (const float4*)x + i * 2;
        float4 a = s[0], b = s[1];
        half8 h;
        h[0] = (_Float16)a.x; h[1] = (_Float16)a.y; h[2] = (_Float16)a.z; h[3] = (_Float16)a.w;
        h[4] = (_Float16)b.x; h[5] = (_Float16)b.y; h[6] = (_Float16)b.z; h[7] = (_Float16)b.w;
        *((half8*)xh + i) = h;
    }
}

// transpose+convert W [k][n] fp32 -> wt [n][k] fp16; blockIdx.x selects matrix
__global__ __launch_bounds__(256) void prep_w(const float* __restrict__ Wq,
                                              const float* __restrict__ Wk,
                                              const float* __restrict__ Wv,
                                              _Float16* __restrict__ wt) {
    const float* W = (blockIdx.x == 0) ? Wq : (blockIdx.x == 1) ? Wk : Wv;
    _Float16* out = wt + (size_t)blockIdx.x * 16384;
    int t = threadIdx.x;
    for (int r = 0; r < 64; ++r) {
        int idx = r * 256 + t;          // idx = k*128 + n
        int k = idx >> 7, nn = idx & 127;
        out[nn * 128 + k] = (_Float16)W[idx];
    }
}

// ---------------- QKV projection: fp16 MFMA ----------------
// grid (ceil(N/128), 3); block 256 = 4 waves, each wave a 64x64 subtile.
// C = x @ W : A = x[m][k], B via wt[n][k].

#define LDP 136  // 128 + 8-halfs pad (16B) to break LDS bank alignment

__global__ __launch_bounds__(256) void qkv_mfma(
    const _Float16* __restrict__ xh, const _Float16* __restrict__ wt,
    const float* __restrict__ bq, const float* __restrict__ bk,
    const float* __restrict__ bv,
    _Float16* __restrict__ qh, _Float16* __restrict__ kh, _Float16* __restrict__ vh,
    int n) {
    __shared__ __align__(16) _Float16 xs[128 * LDP];
    __shared__ __align__(16) _Float16 ws[128 * LDP];

    int t = threadIdx.x;
    int tile0 = blockIdx.x * 128;
    int sel = blockIdx.y;
    const _Float16* wsel = wt + (size_t)sel * 16384;
    const float* bias = (sel == 0) ? bq : (sel == 1) ? bk : bv;
    _Float16* out = (sel == 0) ? qh : (sel == 1) ? kh : vh;

    // stage x tile (128 rows x 16 half8 chunks = 2048 chunks) and W^T tile
#pragma unroll
    for (int r = 0; r < 8; ++r) {
        int id = r * 256 + t;            // 2048 half8 chunks
        int row = id >> 4, c8 = id & 15;
        int grow = tile0 + row;
        half8 val = (half8)(_Float16)0;
        if (grow < n) val = *((const half8*)(xh + (size_t)grow * 128) + c8);
        *((half8*)(xs + row * LDP) + c8) = val;
        half8 wv = *((const half8*)(wsel + row * 128) + c8);
        *((half8*)(ws + row * LDP) + c8) = wv;
    }
    __syncthreads();

    int wave = t >> 6, lane = t & 63;
    int wm = (wave & 1) * 64, wn = (wave >> 1) * 64;
    int lrow = lane & 15, quad = lane >> 4;

    floatx4 acc[4][4];
#pragma unroll
    for (int i = 0; i < 4; ++i)
#pragma unroll
        for (int j = 0; j < 4; ++j) acc[i][j] = (floatx4)0.f;

#pragma unroll
    for (int kk = 0; kk < 4; ++kk) {
        int kbase = kk * 32 + quad * 8;
        half8 a[4], b[4];
#pragma unroll
        for (int i = 0; i < 4; ++i)
            a[i] = *(const half8*)(xs + (wm + i * 16 + lrow) * LDP + kbase);
#pragma unroll
        for (int j = 0; j < 4; ++j)
            b[j] = *(const half8*)(ws + (wn + j * 16 + lrow) * LDP + kbase);
#pragma unroll
        for (int i = 0; i < 4; ++i)
#pragma unroll
            for (int j = 0; j < 4; ++j)
                acc[i][j] = __builtin_amdgcn_mfma_f32_16x16x32_f16(a[i], b[j], acc[i][j], 0, 0, 0);
    }

    // epilogue: C row = wm+i*16+quad*4+reg, col = wn+j*16+lrow
#pragma unroll
    for (int i = 0; i < 4; ++i) {
#pragma unroll
        for (int j = 0; j < 4; ++j) {
            int col = wn + j * 16 + lrow;
            float bv_ = bias[col];
#pragma unroll
            for (int r = 0; r < 4; ++r) {
                int row = wm + i * 16 + quad * 4 + r;
                int grow = tile0 + row;
                if (grow < n) out[(size_t)grow * 128 + col] = (_Float16)(acc[i][j][r] + bv_);
            }
        }
    }
}

// ---------------- Node-centric attention (fp16 gathers, online softmax) ----------------
// One thread per (node, head): 8 threads/node, 32 nodes/block.

__global__ __launch_bounds__(256) void edge_attn(
    const _Float16* __restrict__ qh, const _Float16* __restrict__ kh,
    const _Float16* __restrict__ vh, const float* __restrict__ pi,
    const float* __restrict__ view_w, const int* __restrict__ src,
    const int* __restrict__ row_ptr, const int* __restrict__ csr,
    float* __restrict__ node_out, float* attn_out, int n) {
    int t = threadIdx.x;
    int node = blockIdx.x * 32 + (t >> 3);
    int h = t & 7;
    if (node >= n) return;

    half16v qv = *(const half16v*)(qh + (size_t)node * 128 + h * 16);
    float qf[16];
#pragma unroll
    for (int j = 0; j < 16; ++j) qf[j] = (float)qv[j];

    float p0 = pi[node * 24 + h * 3 + 0];
    float p1 = pi[node * 24 + h * 3 + 1];
    float p2 = pi[node * 24 + h * 3 + 2];
    int beg = row_ptr[node], end = row_ptr[node + 1];

    // fused pass: score + online softmax + weighted V accumulate
    float m = -INFINITY, l = 0.f;
    float acc[16];
#pragma unroll
    for (int j = 0; j < 16; ++j) acc[j] = 0.f;

    for (int i = beg; i < end; ++i) {
        int e = csr[i];
        int s0 = src[e];
        float w0 = view_w[e * 3 + 0], w1 = view_w[e * 3 + 1], w2 = view_w[e * 3 + 2];
        float mix = fmaf(p0, w0, fmaf(p1, w1, p2 * w2));
        half16v kv = *(const half16v*)(kh + (size_t)s0 * 128 + h * 16);
        float dot = 0.f;
#pragma unroll
        for (int j = 0; j < 16; ++j) dot = fmaf(qf[j], (float)kv[j], dot);
        float s = (mix > 0.f) ? (dot * 0.25f + __logf(fmaxf(mix, 1e-8f))) : NEG;
        attn_out[(size_t)e * 8 + h] = s;
        if (s > 0.5f * NEG) {
            if (s > m) {
                float sc = __expf(m - s);
                l *= sc;
#pragma unroll
                for (int j = 0; j < 16; ++j) acc[j] *= sc;
                m = s;
            }
            float w = __expf(s - m);
            l += w;
            half16v vv = *(const half16v*)(vh + (size_t)s0 * 128 + h * 16);
#pragma unroll
            for (int j = 0; j < 16; ++j) acc[j] = fmaf(w, (float)vv[j], acc[j]);
        }
    }

    float inv = 1.f / fmaxf(l, 1e-8f);
    float4* op = (float4*)(node_out + (size_t)node * 128 + h * 16);
#pragma unroll
    for (int j = 0; j < 4; ++j)
        op[j] = make_float4(acc[4 * j] * inv, acc[4 * j + 1] * inv,
                            acc[4 * j + 2] * inv, acc[4 * j + 3] * inv);

    // pass 2: normalize stored scores into attention weights
    for (int i = beg; i < end; ++i) {
        int e = csr[i];
        float s = attn_out[(size_t)e * 8 + h];
        float w = (s <= 0.5f * NEG) ? 0.f : __expf(s - m);
        attn_out[(size_t)e * 8 + h] = w * inv;
    }
}

// ---------------- launch ----------------

extern "C" void kernel_launch(void* const* d_in, const int* in_sizes, int n_in,
                              void* d_out, int out_size, void* d_ws, size_t ws_size,
                              hipStream_t stream) {
    const float* x  = (const float*)d_in[0];
    const float* pi = (const float*)d_in[1];
    const float* vw = (const float*)d_in[2];
    const float* Wq = (const float*)d_in[3];
    const float* bq = (const float*)d_in[4];
    const float* Wk = (const float*)d_in[5];
    const float* bk = (const float*)d_in[6];
    const float* Wv = (const float*)d_in[7];
    const float* bv = (const float*)d_in[8];
    const int* src  = (const int*)d_in[9];
    const int* dst  = (const int*)d_in[10];

    int n = in_sizes[0] / 128;  // 100000
    int e = in_sizes[9];        // 1600000

    _Float16* xh = (_Float16*)d_ws;
    _Float16* qh = xh + (size_t)n * 128;
    _Float16* kh = qh + (size_t)n * 128;
    _Float16* vh = kh + (size_t)n * 128;
    _Float16* wt = vh + (size_t)n * 128;
    int* counts  = (int*)(wt + 3 * 16384);
    int* cursor  = counts + n;
    int* row_ptr = cursor + n;
    int* csr     = row_ptr + n + 1;
    int* bsum    = csr + e;

    float* node_out = (float*)d_out;
    float* attn_out = node_out + (size_t)n * 128;

    hipMemsetAsync(counts, 0, (size_t)n * sizeof(int), stream);

    int eb = (e + 255) / 256;
    hist_kernel<<<eb, 256, 0, stream>>>(dst, counts, e);

    int nb = (n + SCAN_CHUNK - 1) / SCAN_CHUNK;  // 49
    scan_block_sums<<<nb, 256, 0, stream>>>(counts, bsum, n);
    scan_wave<<<1, 64, 0, stream>>>(bsum, nb);
    scan_write<<<nb, 256, 0, stream>>>(counts, bsum, row_ptr, cursor, n, e);
    fill_csr<<<eb, 256, 0, stream>>>(dst, cursor, csr, e);

    int tot8 = (n * 128) / 8;
    convert_x<<<(tot8 + 255) / 256, 256, 0, stream>>>(x, xh, tot8);
    prep_w<<<3, 256, 0, stream>>>(Wq, Wk, Wv, wt);

    int gtiles = (n + 127) / 128;
    qkv_mfma<<<dim3(gtiles, 3), 256, 0, stream>>>(xh, wt, bq, bk, bv, qh, kh, vh, n);

    int gb = (n + 31) / 32;
    edge_attn<<<gb, 256, 0, stream>>>(qh, kh, vh, pi, vw, src, row_ptr, csr,
                                      node_out, attn_out, n);
}